// Round 1
// baseline (130.941 us; speedup 1.0000x reference)
//
#include <hip/hip_runtime.h>
#include <math.h>

#define TSIZE 32
#define PATCH 3072   // 3*32*32
#define WIN 11
#define NB 8
#define NG 16
#define NP 64
#define IMH 640
#define IMW 640

// C1 = (0.01*255)^2, C2 = (0.03*255)^2
#define C1F 6.5025f
#define C2F 58.5225f

__device__ __forceinline__ void gauss_win(float* g) {
    // matches numpy: float64 exp, normalize, cast f32
    double gd[WIN];
    double s = 0.0;
#pragma unroll
    for (int k = 0; k < WIN; ++k) {
        double d = (double)(k - WIN / 2);
        gd[k] = exp(-(d * d) / (2.0 * 1.5 * 1.5));
        s += gd[k];
    }
#pragma unroll
    for (int k = 0; k < WIN; ++k) g[k] = (float)(gd[k] / s);
}

// ---------------------------------------------------------------------------
// K1: one block per box (128 gt + 512 pred). Crop-resize bilinear -> patch,
// then separable 11-tap gaussian conv (zero-padded SAME) of patch and patch^2.
// ---------------------------------------------------------------------------
__global__ __launch_bounds__(256) void gen_patches(
    const float* __restrict__ gt_boxes, const float* __restrict__ pred_boxes,
    const float* __restrict__ imgs,
    float* __restrict__ gt_patch, float* __restrict__ gt_mu, float* __restrict__ gt_gsq,
    float* __restrict__ pr_patch, float* __restrict__ pr_mu, float* __restrict__ pr_gsq)
{
    const int id = blockIdx.x;
    const float* box;
    float *patch_o, *mu_o, *gsq_o;
    int b;
    if (id < NB * NG) {
        b = id / NG;
        box = gt_boxes + (size_t)id * 4;
        patch_o = gt_patch + (size_t)id * PATCH;
        mu_o    = gt_mu    + (size_t)id * PATCH;
        gsq_o   = gt_gsq   + (size_t)id * PATCH;
    } else {
        const int id2 = id - NB * NG;
        b = id2 / NP;
        box = pred_boxes + (size_t)id2 * 4;
        patch_o = pr_patch + (size_t)id2 * PATCH;
        mu_o    = pr_mu    + (size_t)id2 * PATCH;
        gsq_o   = pr_gsq   + (size_t)id2 * PATCH;
    }
    const float* img = imgs + (size_t)b * 3 * IMH * IMW;

    __shared__ int   s_ylo[TSIZE], s_yhi[TSIZE], s_xlo[TSIZE], s_xhi[TSIZE];
    __shared__ float s_wy[TSIZE], s_wx[TSIZE];
    __shared__ float sp[PATCH];
    __shared__ float tmu[PATCH];
    __shared__ float tsq[PATCH];

    const int tid = threadIdx.x;

    {
#pragma clang fp contract(off)
        const float b0 = box[0], b1 = box[1], b2 = box[2], b3 = box[3];
        const float x0 = floorf(b0), y0 = floorf(b1);
        const float w = floorf(b0 + b2) - x0;
        const float h = floorf(b1 + b3) - y0;

        if (tid < TSIZE) {
            const int t = tid;
            const float hm = fmaxf(h - 1.0f, 0.0f);
            const float scale = h / 32.0f;
            float ys = ((float)t + 0.5f) * scale - 0.5f;
            ys = fminf(fmaxf(ys, 0.0f), hm);
            const float yf = floorf(ys);
            s_wy[t] = ys - yf;
            const float ylo = yf + y0;
            const float yhi = fminf(yf + 1.0f, hm) + y0;
            s_ylo[t] = (int)fminf(fmaxf(ylo, 0.0f), (float)(IMH - 1));
            s_yhi[t] = (int)fminf(fmaxf(yhi, 0.0f), (float)(IMH - 1));
        } else if (tid < 2 * TSIZE) {
            const int t = tid - TSIZE;
            const float wm = fmaxf(w - 1.0f, 0.0f);
            const float scale = w / 32.0f;
            float xs = ((float)t + 0.5f) * scale - 0.5f;
            xs = fminf(fmaxf(xs, 0.0f), wm);
            const float xf = floorf(xs);
            s_wx[t] = xs - xf;
            const float xlo = xf + x0;
            const float xhi = fminf(xf + 1.0f, wm) + x0;
            s_xlo[t] = (int)fminf(fmaxf(xlo, 0.0f), (float)(IMW - 1));
            s_xhi[t] = (int)fminf(fmaxf(xhi, 0.0f), (float)(IMW - 1));
        }
    }
    __syncthreads();

    // bilinear gather
    for (int idx = tid; idx < PATCH; idx += 256) {
#pragma clang fp contract(off)
        const int c = idx >> 10;
        const int i = (idx >> 5) & 31;
        const int j = idx & 31;
        const float* ic = img + (size_t)c * IMH * IMW;
        const int ylo = s_ylo[i], yhi = s_yhi[i];
        const int xlo = s_xlo[j], xhi = s_xhi[j];
        const float wy = s_wy[i], wx = s_wx[j];
        const float tl = ic[ylo * IMW + xlo], tr = ic[ylo * IMW + xhi];
        const float bl = ic[yhi * IMW + xlo], br = ic[yhi * IMW + xhi];
        const float top = tl * (1.0f - wx) + tr * wx;
        const float bot = bl * (1.0f - wx) + br * wx;
        const float v = top * (1.0f - wy) + bot * wy;
        sp[idx] = v;
        patch_o[idx] = v;
    }
    __syncthreads();

    float g[WIN];
    gauss_win(g);

    // row conv (along j), zero-padded
    for (int idx = tid; idx < PATCH; idx += 256) {
        const int j = idx & 31;
        const int base = idx - j;
        float am = 0.f, aq = 0.f;
#pragma unroll
        for (int k = 0; k < WIN; ++k) {
            const int jj = j + k - WIN / 2;
            if (jj >= 0 && jj < TSIZE) {
                const float v = sp[base + jj];
                am += g[k] * v;
                aq += g[k] * v * v;
            }
        }
        tmu[idx] = am;
        tsq[idx] = aq;
    }
    __syncthreads();

    // col conv (along i), zero-padded; write mu, gconv(sq)
    for (int idx = tid; idx < PATCH; idx += 256) {
        const int j = idx & 31;
        const int i = (idx >> 5) & 31;
        const int cbase = idx - (i << 5) - j;  // c*1024
        float am = 0.f, aq = 0.f;
#pragma unroll
        for (int k = 0; k < WIN; ++k) {
            const int ii = i + k - WIN / 2;
            if (ii >= 0 && ii < TSIZE) {
                am += g[k] * tmu[cbase + (ii << 5) + j];
                aq += g[k] * tsq[cbase + (ii << 5) + j];
            }
        }
        mu_o[idx] = am;
        gsq_o[idx] = aq;
    }
}

// ---------------------------------------------------------------------------
// K2: one block per (b,g,p) pair. IoU+mask inline; early-out when unmasked.
// Masked: separable conv of x*y in LDS, fused SSIM + L1 epilogue, block
// reduce, atomic accumulate (total, count).
// ---------------------------------------------------------------------------
__global__ __launch_bounds__(256) void pair_kernel(
    const float* __restrict__ gt_boxes, const float* __restrict__ pred_boxes,
    const float* __restrict__ gt_patch, const float* __restrict__ gt_mu, const float* __restrict__ gt_gsq,
    const float* __restrict__ pr_patch, const float* __restrict__ pr_mu, const float* __restrict__ pr_gsq,
    float* __restrict__ accum /* [0]=total (f32), [1]=count (int) */)
{
    const int bid = blockIdx.x;
    const int b   = bid / (NG * NP);
    const int rem = bid % (NG * NP);
    const int gi  = rem / NP;
    const int pi  = rem % NP;

    bool mask;
    {
#pragma clang fp contract(off)
        const float* gb = gt_boxes  + ((size_t)b * NG + gi) * 4;
        const float* pb = pred_boxes + ((size_t)b * NP + pi) * 4;
        const float gx = gb[0], gy = gb[1], gw = gb[2], gh = gb[3];
        const float px = pb[0], py = pb[1], pw = pb[2], ph = pb[3];
        const float tlx = fmaxf(gx - gw / 2.0f, px - pw / 2.0f);
        const float tly = fmaxf(gy - gh / 2.0f, py - ph / 2.0f);
        const float brx = fminf(gx + gw / 2.0f, px + pw / 2.0f);
        const float bry = fminf(gy + gh / 2.0f, py + ph / 2.0f);
        const float en = ((tlx < brx) ? 1.0f : 0.0f) * ((tly < bry) ? 1.0f : 0.0f);
        const float ai = ((brx - tlx) * (bry - tly)) * en;
        const float ag = gw * gh;
        const float ap = pw * ph;
        const float iou = ai / (ag + ap - ai + 1e-16f);
        mask = (iou > 0.3f) && (pw > 2.0f) && (ph > 2.0f);
    }
    if (!mask) return;  // uniform across the block

    const int tid = threadIdx.x;
    if (tid == 0) atomicAdd((int*)(accum + 1), 1);

    const size_t poff = ((size_t)b * NP + pi) * PATCH;
    const size_t goff = ((size_t)b * NG + gi) * PATCH;
    const float* __restrict__ xg  = pr_patch + poff;
    const float* __restrict__ yg  = gt_patch + goff;
    const float* __restrict__ m1g = pr_mu  + poff;
    const float* __restrict__ q1g = pr_gsq + poff;
    const float* __restrict__ m2g = gt_mu  + goff;
    const float* __restrict__ q2g = gt_gsq + goff;

    __shared__ float sx[PATCH];
    __shared__ float sy[PATCH];
    __shared__ float tp[PATCH];
    __shared__ float wred[4];

    for (int idx = tid; idx < PATCH; idx += 256) {
        sx[idx] = xg[idx];
        sy[idx] = yg[idx];
    }
    __syncthreads();

    float g[WIN];
    gauss_win(g);

    // row conv of x*y
    for (int idx = tid; idx < PATCH; idx += 256) {
        const int j = idx & 31;
        const int base = idx - j;
        float a = 0.f;
#pragma unroll
        for (int k = 0; k < WIN; ++k) {
            const int jj = j + k - WIN / 2;
            if (jj >= 0 && jj < TSIZE) {
                a += g[k] * (sx[base + jj] * sy[base + jj]);
            }
        }
        tp[idx] = a;
    }
    __syncthreads();

    // col conv + fused epilogue
    float lsum = 0.0f;
    for (int idx = tid; idx < PATCH; idx += 256) {
        const int j = idx & 31;
        const int i = (idx >> 5) & 31;
        const int cbase = idx - (i << 5) - j;
        float cxy = 0.f;
#pragma unroll
        for (int k = 0; k < WIN; ++k) {
            const int ii = i + k - WIN / 2;
            if (ii >= 0 && ii < TSIZE) {
                cxy += g[k] * tp[cbase + (ii << 5) + j];
            }
        }
        const float mu1 = m1g[idx];
        const float mu2 = m2g[idx];
        const float q1  = q1g[idx];
        const float q2  = q2g[idx];
        const float mu1sq = mu1 * mu1;
        const float mu2sq = mu2 * mu2;
        const float mu12  = mu1 * mu2;
        const float s1  = q1 - mu1sq;
        const float s2  = q2 - mu2sq;
        const float s12 = cxy - mu12;
        const float num = (2.0f * mu12 + C1F) * (2.0f * s12 + C2F);
        const float den = (mu1sq + mu2sq + C1F) * (s1 + s2 + C2F);
        const float ssim = num / den;
        const float xv = sx[idx], yv = sy[idx];
        lsum += fabsf(xv / 255.0f - yv / 255.0f) + (1.0f - ssim);
    }

    // block reduce (4 waves of 64)
#pragma unroll
    for (int off = 32; off > 0; off >>= 1) lsum += __shfl_down(lsum, off);
    if ((tid & 63) == 0) wred[tid >> 6] = lsum;
    __syncthreads();
    if (tid == 0) {
        atomicAdd(accum, wred[0] + wred[1] + wred[2] + wred[3]);
    }
}

__global__ void finalize_kernel(const float* __restrict__ accum, float* __restrict__ out) {
    const float total = accum[0];
    const int n = *(const int*)(accum + 1);
    out[0] = (n > 0) ? (total / ((float)n * 3072.0f)) : 0.0f;
}

extern "C" void kernel_launch(void* const* d_in, const int* in_sizes, int n_in,
                              void* d_out, int out_size, void* d_ws, size_t ws_size,
                              hipStream_t stream) {
    const float* gt_boxes   = (const float*)d_in[0];  // (8,16,4)
    const float* pred_boxes = (const float*)d_in[1];  // (8,64,4)
    const float* imgs       = (const float*)d_in[2];  // (8,3,640,640)

    float* ws = (float*)d_ws;
    const size_t ng = (size_t)NB * NG;   // 128
    const size_t np = (size_t)NB * NP;   // 512
    float* gt_patch = ws;
    float* gt_mu    = gt_patch + ng * PATCH;
    float* gt_gsq   = gt_mu    + ng * PATCH;
    float* pr_patch = gt_gsq   + ng * PATCH;
    float* pr_mu    = pr_patch + np * PATCH;
    float* pr_gsq   = pr_mu    + np * PATCH;
    float* accum    = pr_gsq   + np * PATCH;  // [0]=total, [1]=count

    hipMemsetAsync(accum, 0, 2 * sizeof(float), stream);

    gen_patches<<<(int)(ng + np), 256, 0, stream>>>(
        gt_boxes, pred_boxes, imgs,
        gt_patch, gt_mu, gt_gsq, pr_patch, pr_mu, pr_gsq);

    pair_kernel<<<NB * NG * NP, 256, 0, stream>>>(
        gt_boxes, pred_boxes,
        gt_patch, gt_mu, gt_gsq, pr_patch, pr_mu, pr_gsq, accum);

    finalize_kernel<<<1, 1, 0, stream>>>(accum, (float*)d_out);
}

// Round 2
// 103.959 us; speedup vs baseline: 1.2595x; 1.2595x over previous
//
#include <hip/hip_runtime.h>
#include <math.h>

#define TSIZE 32
#define WIN 11
#define NB 8
#define NG 16
#define NP 64
#define IMH 640
#define IMW 640
#define NBOX 640          // 128 gt + 512 pred
#define NPAIR 8192        // 8*16*64

#define C1F 6.5025f
#define C2F 58.5225f

struct GaussW { float g[WIN]; };
struct f4 { float v[4]; };

// ---------------------------------------------------------------------------
// K1: blocks [0, 1920): one block per (box, channel). Crop-resize bilinear ->
// patch (1024 px), separable 11-tap gaussian conv (zero-pad SAME) of patch
// and patch^2. blocks [1920, 1952): IoU mask compaction of 8192 pairs.
// ---------------------------------------------------------------------------
__global__ __launch_bounds__(256) void gen_patches(
    const float* __restrict__ gt_boxes, const float* __restrict__ pred_boxes,
    const float* __restrict__ imgs,
    float* __restrict__ patches, float* __restrict__ mus, float* __restrict__ gsqs,
    int* __restrict__ pair_list, int* __restrict__ pair_cnt, GaussW gw)
{
    const int bid = blockIdx.x;
    const int tid = threadIdx.x;

    if (bid >= NBOX * 3) {
        // ---- mask compaction ----
        const int p = (bid - NBOX * 3) * 256 + tid;   // [0, 8192)
        const int b  = p >> 10;
        const int gi = (p >> 6) & 15;
        const int pi = p & 63;
        bool mask;
        {
#pragma clang fp contract(off)
            const float* gb = gt_boxes  + ((size_t)b * NG + gi) * 4;
            const float* pb = pred_boxes + ((size_t)b * NP + pi) * 4;
            const float gx = gb[0], gy = gb[1], gw_ = gb[2], gh = gb[3];
            const float px = pb[0], py = pb[1], pw = pb[2], ph = pb[3];
            const float tlx = fmaxf(gx - gw_ / 2.0f, px - pw / 2.0f);
            const float tly = fmaxf(gy - gh / 2.0f, py - ph / 2.0f);
            const float brx = fminf(gx + gw_ / 2.0f, px + pw / 2.0f);
            const float bry = fminf(gy + gh / 2.0f, py + ph / 2.0f);
            const float en = ((tlx < brx) ? 1.0f : 0.0f) * ((tly < bry) ? 1.0f : 0.0f);
            const float ai = ((brx - tlx) * (bry - tly)) * en;
            const float ag = gw_ * gh;
            const float ap = pw * ph;
            const float iou = ai / (ag + ap - ai + 1e-16f);
            mask = (iou > 0.3f) && (pw > 2.0f) && (ph > 2.0f);
        }
        if (mask) {
            const int slot = atomicAdd(pair_cnt, 1);
            pair_list[slot] = p;
        }
        return;
    }

    // ---- patch generation ----
    const int box = bid / 3;
    const int c   = bid - box * 3;
    int b;
    const float* boxp;
    if (box < NB * NG) {
        b = box >> 4;
        boxp = gt_boxes + (size_t)box * 4;
    } else {
        const int q = box - NB * NG;
        b = q >> 6;
        boxp = pred_boxes + (size_t)q * 4;
    }
    const float* __restrict__ ic = imgs + ((size_t)b * 3 + c) * (IMH * IMW);
    float* __restrict__ patch_o = patches + ((size_t)box * 3 + c) * 1024;
    float* __restrict__ mu_o    = mus     + ((size_t)box * 3 + c) * 1024;
    float* __restrict__ gsq_o   = gsqs    + ((size_t)box * 3 + c) * 1024;

    __shared__ int   s_ylo[TSIZE], s_yhi[TSIZE], s_xlo[TSIZE], s_xhi[TSIZE];
    __shared__ float s_wy[TSIZE], s_wx[TSIZE];
    __shared__ float sp[1024], ta[1024], tb[1024];

    {
#pragma clang fp contract(off)
        const float b0 = boxp[0], b1 = boxp[1], b2 = boxp[2], b3 = boxp[3];
        const float x0 = floorf(b0), y0 = floorf(b1);
        const float w = floorf(b0 + b2) - x0;
        const float h = floorf(b1 + b3) - y0;

        if (tid < TSIZE) {
            const int t = tid;
            const float hm = fmaxf(h - 1.0f, 0.0f);
            const float scale = h / 32.0f;
            float ys = ((float)t + 0.5f) * scale - 0.5f;
            ys = fminf(fmaxf(ys, 0.0f), hm);
            const float yf = floorf(ys);
            s_wy[t] = ys - yf;
            const float ylo = yf + y0;
            const float yhi = fminf(yf + 1.0f, hm) + y0;
            s_ylo[t] = (int)fminf(fmaxf(ylo, 0.0f), (float)(IMH - 1));
            s_yhi[t] = (int)fminf(fmaxf(yhi, 0.0f), (float)(IMH - 1));
        } else if (tid < 2 * TSIZE) {
            const int t = tid - TSIZE;
            const float wm = fmaxf(w - 1.0f, 0.0f);
            const float scale = w / 32.0f;
            float xs = ((float)t + 0.5f) * scale - 0.5f;
            xs = fminf(fmaxf(xs, 0.0f), wm);
            const float xf = floorf(xs);
            s_wx[t] = xs - xf;
            const float xlo = xf + x0;
            const float xhi = fminf(xf + 1.0f, wm) + x0;
            s_xlo[t] = (int)fminf(fmaxf(xlo, 0.0f), (float)(IMW - 1));
            s_xhi[t] = (int)fminf(fmaxf(xhi, 0.0f), (float)(IMW - 1));
        }
    }
    __syncthreads();

    const int i  = tid >> 3;            // row 0..31 (8 threads per row)
    const int j4 = (tid & 7) << 2;      // col group: 4 consecutive cols
    const int e4 = (i << 5) + j4;

    // bilinear gather: 4 px per thread
    {
        const int ylo = s_ylo[i], yhi = s_yhi[i];
        const float wy = s_wy[i];
        float vv[4];
#pragma unroll
        for (int q = 0; q < 4; ++q) {
#pragma clang fp contract(off)
            const int j = j4 + q;
            const int xlo = s_xlo[j], xhi = s_xhi[j];
            const float wx = s_wx[j];
            const float tl = ic[ylo * IMW + xlo], tr = ic[ylo * IMW + xhi];
            const float bl = ic[yhi * IMW + xlo], br = ic[yhi * IMW + xhi];
            const float top = tl * (1.0f - wx) + tr * wx;
            const float bot = bl * (1.0f - wx) + br * wx;
            vv[q] = top * (1.0f - wy) + bot * wy;
        }
        f4 o; o.v[0] = vv[0]; o.v[1] = vv[1]; o.v[2] = vv[2]; o.v[3] = vv[3];
        *(f4*)&sp[e4] = o;
        *(f4*)&patch_o[e4] = o;
    }
    __syncthreads();

    // row conv (along j), zero-padded: 14-tap register window -> 4 outputs
    {
        float pv[14];
#pragma unroll
        for (int k = 0; k < 14; ++k) {
            const int jj = j4 - 5 + k;
            pv[k] = (jj >= 0 && jj < TSIZE) ? sp[(i << 5) + jj] : 0.0f;
        }
        float am[4] = {0.f, 0.f, 0.f, 0.f};
        float aq[4] = {0.f, 0.f, 0.f, 0.f};
#pragma unroll
        for (int k = 0; k < WIN; ++k) {
            const float gk = gw.g[k];
#pragma unroll
            for (int q = 0; q < 4; ++q) {
                const float v = pv[k + q];
                am[q] += gk * v;
                aq[q] += gk * (v * v);
            }
        }
        f4 oa; f4 ob;
#pragma unroll
        for (int q = 0; q < 4; ++q) { oa.v[q] = am[q]; ob.v[q] = aq[q]; }
        *(f4*)&ta[e4] = oa;
        *(f4*)&tb[e4] = ob;
    }
    __syncthreads();

    // col conv (along i), zero-padded; float4 LDS reads
    {
        float cm[4] = {0.f, 0.f, 0.f, 0.f};
        float cq[4] = {0.f, 0.f, 0.f, 0.f};
#pragma unroll
        for (int k = 0; k < WIN; ++k) {
            const int ii = i - 5 + k;
            if (ii >= 0 && ii < TSIZE) {
                const float gk = gw.g[k];
                const f4 m4 = *(const f4*)&ta[(ii << 5) + j4];
                const f4 q4 = *(const f4*)&tb[(ii << 5) + j4];
#pragma unroll
                for (int q = 0; q < 4; ++q) {
                    cm[q] += gk * m4.v[q];
                    cq[q] += gk * q4.v[q];
                }
            }
        }
        f4 om; f4 oq;
#pragma unroll
        for (int q = 0; q < 4; ++q) { om.v[q] = cm[q]; oq.v[q] = cq[q]; }
        *(f4*)&mu_o[e4]  = om;
        *(f4*)&gsq_o[e4] = oq;
    }
}

// ---------------------------------------------------------------------------
// K2: fixed grid, grid-stride over (active pair, channel) work items.
// Separable conv of x*y in LDS, fused SSIM + L1 epilogue, block reduce,
// atomic-free partial[w] write.
// ---------------------------------------------------------------------------
__global__ __launch_bounds__(256) void pair_kernel(
    const float* __restrict__ patches, const float* __restrict__ mus,
    const float* __restrict__ gsqs,
    const int* __restrict__ pair_list, const int* __restrict__ pair_cnt,
    float* __restrict__ partial, GaussW gw)
{
    __shared__ float sx[1024], sy[1024], tp[1024];
    __shared__ float wred[4];
    const int tid = threadIdx.x;
    const int nw = pair_cnt[0] * 3;
    const int i  = tid >> 3;
    const int j4 = (tid & 7) << 2;
    const int e4 = (i << 5) + j4;

    for (int w = blockIdx.x; w < nw; w += gridDim.x) {
        const int k3 = w / 3;
        const int c  = w - k3 * 3;
        const int p  = pair_list[k3];
        const int b  = p >> 10;
        const int gi = (p >> 6) & 15;
        const int pi = p & 63;
        const int gbox = b * NG + gi;
        const int pbox = NB * NG + b * NP + pi;
        const size_t po = ((size_t)pbox * 3 + c) * 1024;
        const size_t go = ((size_t)gbox * 3 + c) * 1024;

        const f4 xv = *(const f4*)&patches[po + e4];
        const f4 yv = *(const f4*)&patches[go + e4];
        *(f4*)&sx[e4] = xv;
        *(f4*)&sy[e4] = yv;
        __syncthreads();

        // row conv of x*y
        {
            float pv[14];
#pragma unroll
            for (int k = 0; k < 14; ++k) {
                const int jj = j4 - 5 + k;
                pv[k] = (jj >= 0 && jj < TSIZE)
                        ? sx[(i << 5) + jj] * sy[(i << 5) + jj] : 0.0f;
            }
            float a[4] = {0.f, 0.f, 0.f, 0.f};
#pragma unroll
            for (int k = 0; k < WIN; ++k) {
                const float gk = gw.g[k];
#pragma unroll
                for (int q = 0; q < 4; ++q) a[q] += gk * pv[k + q];
            }
            f4 o;
#pragma unroll
            for (int q = 0; q < 4; ++q) o.v[q] = a[q];
            *(f4*)&tp[e4] = o;
        }
        __syncthreads();

        // col conv + fused epilogue
        float lsum = 0.0f;
        {
            float cxy[4] = {0.f, 0.f, 0.f, 0.f};
#pragma unroll
            for (int k = 0; k < WIN; ++k) {
                const int ii = i - 5 + k;
                if (ii >= 0 && ii < TSIZE) {
                    const float gk = gw.g[k];
                    const f4 t4 = *(const f4*)&tp[(ii << 5) + j4];
#pragma unroll
                    for (int q = 0; q < 4; ++q) cxy[q] += gk * t4.v[q];
                }
            }
            const f4 mu1 = *(const f4*)&mus[po + e4];
            const f4 mu2 = *(const f4*)&mus[go + e4];
            const f4 q1  = *(const f4*)&gsqs[po + e4];
            const f4 q2  = *(const f4*)&gsqs[go + e4];
#pragma unroll
            for (int q = 0; q < 4; ++q) {
                const float m1 = mu1.v[q], m2 = mu2.v[q];
                const float m1s = m1 * m1, m2s = m2 * m2, m12 = m1 * m2;
                const float s1  = q1.v[q] - m1s;
                const float s2  = q2.v[q] - m2s;
                const float s12 = cxy[q] - m12;
                const float num = (2.0f * m12 + C1F) * (2.0f * s12 + C2F);
                const float den = (m1s + m2s + C1F) * (s1 + s2 + C2F);
                const float ssim = num / den;
                lsum += fabsf(xv.v[q] / 255.0f - yv.v[q] / 255.0f) + (1.0f - ssim);
            }
        }

        // block reduce (4 waves of 64), atomic-free partial write
#pragma unroll
        for (int off = 32; off > 0; off >>= 1) lsum += __shfl_down(lsum, off);
        if ((tid & 63) == 0) wred[tid >> 6] = lsum;
        __syncthreads();
        if (tid == 0) partial[w] = wred[0] + wred[1] + wred[2] + wred[3];
        __syncthreads();   // protect LDS reuse on next iteration
    }
}

__global__ __launch_bounds__(256) void finalize_kernel(
    const int* __restrict__ pair_cnt, const float* __restrict__ partial,
    float* __restrict__ out)
{
    __shared__ float wred[4];
    const int tid = threadIdx.x;
    const int n = pair_cnt[0];
    const int nw = n * 3;
    float lsum = 0.0f;
    for (int w = tid; w < nw; w += 256) lsum += partial[w];
#pragma unroll
    for (int off = 32; off > 0; off >>= 1) lsum += __shfl_down(lsum, off);
    if ((tid & 63) == 0) wred[tid >> 6] = lsum;
    __syncthreads();
    if (tid == 0) {
        const float total = wred[0] + wred[1] + wred[2] + wred[3];
        out[0] = (n > 0) ? (total / ((float)n * 3072.0f)) : 0.0f;
    }
}

extern "C" void kernel_launch(void* const* d_in, const int* in_sizes, int n_in,
                              void* d_out, int out_size, void* d_ws, size_t ws_size,
                              hipStream_t stream) {
    const float* gt_boxes   = (const float*)d_in[0];  // (8,16,4)
    const float* pred_boxes = (const float*)d_in[1];  // (8,64,4)
    const float* imgs       = (const float*)d_in[2];  // (8,3,640,640)

    GaussW gw;
    {
        double gd[WIN]; double s = 0.0;
        for (int k = 0; k < WIN; ++k) {
            const double d = (double)(k - WIN / 2);
            gd[k] = exp(-(d * d) / (2.0 * 1.5 * 1.5));
            s += gd[k];
        }
        for (int k = 0; k < WIN; ++k) gw.g[k] = (float)(gd[k] / s);
    }

    float* ws = (float*)d_ws;
    float* patches = ws;                               // 640*3072
    float* mus     = patches + (size_t)NBOX * 3072;
    float* gsqs    = mus     + (size_t)NBOX * 3072;
    float* partial = gsqs    + (size_t)NBOX * 3072;    // 3*8192
    int* pair_list = (int*)(partial + 3 * NPAIR);      // 8192
    int* pair_cnt  = pair_list + NPAIR;                // 1

    hipMemsetAsync(pair_cnt, 0, sizeof(int), stream);

    gen_patches<<<NBOX * 3 + NPAIR / 256, 256, 0, stream>>>(
        gt_boxes, pred_boxes, imgs, patches, mus, gsqs, pair_list, pair_cnt, gw);

    pair_kernel<<<1536, 256, 0, stream>>>(
        patches, mus, gsqs, pair_list, pair_cnt, partial, gw);

    finalize_kernel<<<1, 256, 0, stream>>>(pair_cnt, partial, (float*)d_out);
}